// Round 5
// baseline (103.989 us; speedup 1.0000x reference)
//
#include <hip/hip_runtime.h>
#include <math.h>
#include <string.h>

#define N 12288
#define TILE 96           // j-points per (bx,by) block
#define ACCS 8            // i-points per thread
#define IB (256 * ACCS)   // 2048 i-points per block
#define NBX (N / IB)      // 6
#define NBY (N / TILE)    // 128  -> grid 768 = exactly 3 blocks/CU

typedef unsigned long long ull;

struct CMat { float c[6][6]; };

// ---------------------------------------------------------------------------
// Kernel P: transform j-points to (-2x, -2y, -2z, sqj_masked) in global mem.
// This makes nn's inner-loop j-data a pure wave-uniform read-only stream
// (scalar-pipe s_load / broadcast global_load — no LDS, no __syncthreads).
// ---------------------------------------------------------------------------
__global__ __launch_bounds__(256) void prep_kernel(
    const float* __restrict__ new_xyz,
    const float* __restrict__ gt_sdf,
    float4* __restrict__ gj)
{
    const int j = blockIdx.x * 256 + threadIdx.x;
    const float px = new_xyz[3 * j + 0];
    const float py = new_xyz[3 * j + 1];
    const float pz = new_xyz[3 * j + 2];
    const float sqj = px * px + py * py + pz * pz;
    const bool ins = gt_sdf[j] < 1e-8f;
    gj[j] = make_float4(-2.0f * px, -2.0f * py, -2.0f * pz,
                        ins ? sqj : 3e30f);
}

// ---------------------------------------------------------------------------
// Kernel A: brute-force masked NN. Block (bx,by) owns i in [bx*2048, +2048)
// (8 per thread) and j in [by*96, +96) streamed from gj (uniform index).
// Key d' = sqj_masked - 2*dot via fma chain (z,y,x order — same rounding as
// round 4, which matched the reference argmin exactly). sqi added in reducer.
// Writes (monotone-key<<32 | j) to private slot packed[by*N + i].
// ---------------------------------------------------------------------------
template<bool CAREFUL>
__device__ __forceinline__ void nn_inner(
    const float4* __restrict__ gj, int jbase,
    const float* wx, const float* wy, const float* wz,
    const int* kx,
    float* bd, int* bk)
{
    #pragma unroll 8
    for (int k = 0; k < TILE; ++k) {
        const float4 b = gj[jbase + k];   // wave-uniform -> scalar load
        #pragma unroll
        for (int a = 0; a < ACCS; ++a) {
            float d = fmaf(wz[a], b.z, b.w);
            d = fmaf(wy[a], b.y, d);
            d = fmaf(wx[a], b.x, d);
            bool ok = d < bd[a];
            if (CAREFUL) ok = ok && (k != kx[a]);
            if (ok) { bd[a] = d; bk[a] = k; }
        }
    }
}

__global__ __launch_bounds__(256, 3) void nn_kernel(
    const float* __restrict__ new_xyz,
    const float4* __restrict__ gj,
    ull* __restrict__ packed)
{
    const int tid = threadIdx.x;
    const int bx = blockIdx.x;
    const int by = blockIdx.y;

    const int ibase = bx * IB;
    const int ibase_t = ibase + tid;   // i of acc a is ibase_t + a*256
    const int jbase = by * TILE;

    float wx[ACCS], wy[ACCS], wz[ACCS];
    int kx[ACCS];
    #pragma unroll
    for (int a = 0; a < ACCS; ++a) {
        const int ia = ibase_t + a * 256;
        wx[a] = new_xyz[3 * ia + 0];
        wy[a] = new_xyz[3 * ia + 1];
        wz[a] = new_xyz[3 * ia + 2];
        kx[a] = ia - jbase;            // colliding k (self), if in [0,TILE)
    }

    float bd[ACCS];
    int bk[ACCS];
    #pragma unroll
    for (int a = 0; a < ACCS; ++a) { bd[a] = 3.0e38f; bk[a] = 0; }

    // dirty iff this block's j-tile intersects its i-range (uniform branch)
    const bool dirty = (jbase < ibase + IB) && (jbase + TILE > ibase);
    if (dirty)
        nn_inner<true>(gj, jbase, wx, wy, wz, kx, bd, bk);
    else
        nn_inner<false>(gj, jbase, wx, wy, wz, kx, bd, bk);

    #pragma unroll
    for (int a = 0; a < ACCS; ++a) {
        unsigned kb = __float_as_uint(bd[a]);
        kb = ((int)kb < 0) ? ~kb : (kb | 0x80000000u);
        packed[(size_t)by * N + (ibase_t + a * 256)] =
            ((ull)kb << 32) | (ull)(unsigned)(jbase + bk[a]);
    }
}

// ---------------------------------------------------------------------------
// Kernel B: per-i u64-min over the 128 split slots (4 threads per point,
// 32 slots each, shuffle-min), strain quadratic form, block partials.
// Block covers 64 points; grid = N/64 = 192 blocks.
// ---------------------------------------------------------------------------
__global__ __launch_bounds__(256) void loss_kernel(
    const float* __restrict__ new_xyz,
    const float* __restrict__ xyz,
    const float* __restrict__ gt_sdf,
    const ull* __restrict__ packed,
    double* __restrict__ partial_sum,
    unsigned int* __restrict__ partial_cnt,
    CMat C)
{
    const int tid = threadIdx.x;
    const int il = tid >> 2;          // 0..63 : point within block
    const int chunk = tid & 3;        // 0..3  : split-chunk
    const int i = blockIdx.x * 64 + il;

    ull best = ~0ull;
    #pragma unroll 8
    for (int s = 0; s < NBY / 4; ++s) {
        const ull p = packed[(size_t)(chunk * (NBY / 4) + s) * N + i];
        best = (p < best) ? p : best;
    }
    {   // min over the 4 chunk-threads (adjacent lanes)
        ull o = __shfl_xor(best, 1, 64);
        best = (o < best) ? o : best;
        o = __shfl_xor(best, 2, 64);
        best = (o < best) ? o : best;
    }

    __shared__ ull bmin[64];
    if ((tid & 3) == 0) bmin[il] = best;
    __syncthreads();

    if (tid < 64) {
        const int ii = blockIdx.x * 64 + tid;
        const ull b = bmin[tid];
        const unsigned kb = (unsigned)(b >> 32);
        const unsigned bits = (kb & 0x80000000u) ? (kb ^ 0x80000000u) : ~kb;
        const float key = __uint_as_float(bits);   // min_j (sqj_masked - 2*dot)
        const int nn = (int)(unsigned)(b & 0xffffffffu);

        const float wix = new_xyz[3 * ii + 0];
        const float wiy = new_xyz[3 * ii + 1];
        const float wiz = new_xyz[3 * ii + 2];
        const float sqi = wix * wix + wiy * wiy + wiz * wiz;

        const float d2 = sqi + key;
        const float nnd = sqrtf(fmaxf(d2, 0.0f));
        const bool inside = gt_sdf[ii] < 1e-8f;
        const bool valid = inside && (nnd > 1e-8f);

        float q = 0.0f;
        if (valid) {
            const float xix = xyz[3 * ii + 0], xiy = xyz[3 * ii + 1], xiz = xyz[3 * ii + 2];
            const float wnx = new_xyz[3 * nn + 0], wny = new_xyz[3 * nn + 1], wnz = new_xyz[3 * nn + 2];
            const float xnx = xyz[3 * nn + 0],     xny = xyz[3 * nn + 1],     xnz = xyz[3 * nn + 2];

            const float du = (wnx - xnx) - (wix - xix);
            const float dv = (wny - xny) - (wiy - xiy);
            const float dw = (wnz - xnz) - (wiz - xiz);
            const float dx = wnx - wix + 1e-8f;
            const float dy = wny - wiy + 1e-8f;
            const float dz = wnz - wiz + 1e-8f;

            float et[6];
            et[0] = du / dx;
            et[1] = dv / dy;
            et[2] = dw / dz;
            et[3] = (du / dy + dv / dx) * 0.5f;
            et[4] = (du / dz + dw / dx) * 0.5f;
            et[5] = (dw / dy + dv / dz) * 0.5f;

            #pragma unroll
            for (int a = 0; a < 6; ++a) {
                float s = 0.0f;
                #pragma unroll
                for (int b2 = 0; b2 < 6; ++b2) s += C.c[a][b2] * et[b2];
                q += et[a] * s;
            }
        }

        // single-wave reduction (threads 0..63 are wave 0)
        double q2 = (double)q * (double)q;
        #pragma unroll
        for (int off = 32; off > 0; off >>= 1)
            q2 += __shfl_down(q2, off, 64);
        const ull vm = __ballot(valid);
        if (tid == 0) {
            partial_sum[blockIdx.x] = q2;
            partial_cnt[blockIdx.x] = (unsigned)__popcll(vm);
        }
    }
}

// ---------------------------------------------------------------------------
// Kernel C: finalize — sum 192 partials, out = sqrt(sum q^2) / n_valid
// ---------------------------------------------------------------------------
#define NPART (N / 64)   // 192

__global__ void final_kernel(const double* __restrict__ partial_sum,
                             const unsigned int* __restrict__ partial_cnt,
                             float* __restrict__ out)
{
    const int lane = threadIdx.x;   // 64 threads
    double s = 0.0, c = 0.0;
    #pragma unroll
    for (int k = 0; k < NPART / 64; ++k) {
        s += partial_sum[lane + 64 * k];
        c += (double)partial_cnt[lane + 64 * k];
    }
    #pragma unroll
    for (int off = 32; off > 0; off >>= 1) {
        s += __shfl_down(s, off, 64);
        c += __shfl_down(c, off, 64);
    }
    if (lane == 0) out[0] = (float)(sqrt(s) / c);
}

// ---------------- Host: build C = inv(Ci) -----------------------------------
static void build_cmat(CMat* M)
{
    const double VP = 0.4, EP = 0.21;
    double A[6][12];
    memset(A, 0, sizeof(A));
    double Ci[6][6];
    memset(Ci, 0, sizeof(Ci));
    Ci[0][0] = 1.0 / EP; Ci[0][1] = -VP / EP; Ci[0][2] = -VP / EP;
    Ci[1][0] = -VP / EP; Ci[1][1] = 1.0 / EP; Ci[1][2] = -VP / EP;
    Ci[2][0] = -VP;      Ci[2][1] = -VP;      Ci[2][2] = 1.0 / EP;
    Ci[3][3] = 2.0 * (1.0 + VP) / EP;
    Ci[4][4] = Ci[3][3];
    Ci[5][5] = Ci[3][3];

    for (int i = 0; i < 6; ++i) {
        for (int j = 0; j < 6; ++j) A[i][j] = Ci[i][j];
        A[i][6 + i] = 1.0;
    }
    for (int col = 0; col < 6; ++col) {
        int piv = col;
        for (int r = col + 1; r < 6; ++r)
            if (fabs(A[r][col]) > fabs(A[piv][col])) piv = r;
        if (piv != col)
            for (int c = 0; c < 12; ++c) { double t = A[col][c]; A[col][c] = A[piv][c]; A[piv][c] = t; }
        const double d = A[col][col];
        for (int c = 0; c < 12; ++c) A[col][c] /= d;
        for (int r = 0; r < 6; ++r) {
            if (r == col) continue;
            const double f = A[r][col];
            if (f == 0.0) continue;
            for (int c = 0; c < 12; ++c) A[r][c] -= f * A[col][c];
        }
    }
    for (int i = 0; i < 6; ++i)
        for (int j = 0; j < 6; ++j)
            M->c[i][j] = (float)A[i][6 + j];
}

extern "C" void kernel_launch(void* const* d_in, const int* in_sizes, int n_in,
                              void* d_out, int out_size, void* d_ws, size_t ws_size,
                              hipStream_t stream)
{
    const float* new_xyz = (const float*)d_in[0];
    const float* xyz     = (const float*)d_in[1];
    const float* gt_sdf  = (const float*)d_in[2];
    float* out = (float*)d_out;

    // workspace layout (fully written before read — no memset needed):
    //   [0, NBY*N*8)          : packed u64 per (split, i)        (12.6 MB)
    //   [+0, N*16)            : gj float4 transformed j-points   (196 KB)
    //   then NPART doubles (partial_sum), NPART uints (partial_cnt)
    const size_t packed_bytes = (size_t)NBY * N * sizeof(ull);
    ull* packed = (ull*)d_ws;
    float4* gj = (float4*)((char*)d_ws + packed_bytes);
    double* partial_sum = (double*)((char*)d_ws + packed_bytes + (size_t)N * 16);
    unsigned int* partial_cnt =
        (unsigned int*)((char*)partial_sum + NPART * sizeof(double));

    CMat C;
    build_cmat(&C);

    prep_kernel<<<N / 256, 256, 0, stream>>>(new_xyz, gt_sdf, gj);
    nn_kernel<<<dim3(NBX, NBY), 256, 0, stream>>>(new_xyz, gj, packed);
    loss_kernel<<<N / 64, 256, 0, stream>>>(new_xyz, xyz, gt_sdf, packed,
                                            partial_sum, partial_cnt, C);
    final_kernel<<<1, 64, 0, stream>>>(partial_sum, partial_cnt, out);
}

// Round 6
// 92.777 us; speedup vs baseline: 1.1209x; 1.1209x over previous
//
#include <hip/hip_runtime.h>
#include <math.h>
#include <string.h>

#define N 12288
#define TILE 96           // j-points per block (one LDS tile); < 128 (7 idx bits)
#define ACCS 6            // i-points per thread
#define IB (256 * ACCS)   // 1536 i-points per block
#define NBX (N / IB)      // 8
#define NBY (N / TILE)    // 128  -> grid 1024 = exactly 4 blocks/CU

typedef unsigned long long ull;

struct CMat { float c[6][6]; };

// ---------------------------------------------------------------------------
// Kernel A: brute-force masked NN, compare-free inner loop.
// Tile holds (-2x, -2y, -2z, sqj_masked + 1) so the fma chain yields
// dB = d2 + 1 >= ~1 (positive => u32 bit order == float order).
// key = (bits(dB) & ~127) | k  packs the tile-local index into the low
// 7 mantissa bits; running argmin is a single v_min_u32 — no v_cmp, no
// vcc/sgpr-mask hazard in the hot loop. sqi cancels out of the ordering
// (constant per i) and is re-derived in the reducer via d2 = key_f - 1.
// ---------------------------------------------------------------------------
template<bool CAREFUL>
__device__ __forceinline__ void nn_inner(
    const float4* __restrict__ tile,
    const float* wx, const float* wy, const float* wz,
    const float* sqi,
    const int* kx,
    unsigned* bm)
{
    #pragma unroll 8
    for (int k = 0; k < TILE; ++k) {
        const float4 b = tile[k];
        #pragma unroll
        for (int a = 0; a < ACCS; ++a) {
            float t = fmaf(wz[a], b.z, b.w);
            t = fmaf(wy[a], b.y, t);
            t = fmaf(wx[a], b.x, t);
            const float dB = t + sqi[a];           // = d2 + 1 (>= ~1)
            unsigned key = (__float_as_uint(dB) & 0xFFFFFF80u) | (unsigned)k;
            if (CAREFUL && k == kx[a]) key = 0xFFFFFFFFu;   // exclude self
            bm[a] = min(bm[a], key);
        }
    }
}

__global__ __launch_bounds__(256, 4) void nn_kernel(
    const float* __restrict__ new_xyz,
    const float* __restrict__ gt_sdf,
    ull* __restrict__ packed)
{
    const int tid = threadIdx.x;
    const int bx = blockIdx.x;
    const int by = blockIdx.y;

    const int ibase = bx * IB;
    const int ibase_t = ibase + tid;   // i of acc a is ibase_t + a*256
    const int jbase = by * TILE;

    float wx[ACCS], wy[ACCS], wz[ACCS], sqi[ACCS];
    int kx[ACCS];
    #pragma unroll
    for (int a = 0; a < ACCS; ++a) {
        const int ia = ibase_t + a * 256;
        wx[a] = new_xyz[3 * ia + 0];
        wy[a] = new_xyz[3 * ia + 1];
        wz[a] = new_xyz[3 * ia + 2];
        sqi[a] = wx[a] * wx[a] + wy[a] * wy[a] + wz[a] * wz[a];
        kx[a] = ia - jbase;            // colliding k (self), if in [0,TILE)
    }

    __shared__ float4 tile[TILE];
    if (tid < TILE) {
        const int j = jbase + tid;
        const float px = new_xyz[3 * j + 0];
        const float py = new_xyz[3 * j + 1];
        const float pz = new_xyz[3 * j + 2];
        const float sqj = px * px + py * py + pz * pz;
        const bool ins = gt_sdf[j] < 1e-8f;
        tile[tid] = make_float4(-2.0f * px, -2.0f * py, -2.0f * pz,
                                ins ? (sqj + 1.0f) : 3e30f);
    }
    __syncthreads();

    unsigned bm[ACCS];
    #pragma unroll
    for (int a = 0; a < ACCS; ++a) bm[a] = 0xFFFFFFFFu;

    // dirty iff this block's j-tile intersects its i-range (uniform branch)
    const bool dirty = (jbase < ibase + IB) && (jbase + TILE > ibase);
    if (dirty)
        nn_inner<true>(tile, wx, wy, wz, sqi, kx, bm);
    else
        nn_inner<false>(tile, wx, wy, wz, sqi, kx, bm);

    #pragma unroll
    for (int a = 0; a < ACCS; ++a) {
        const unsigned kwin = bm[a] & 127u;          // winning tile-local k
        const unsigned keyc = bm[a] & 0xFFFFFF80u;   // quantized dB bits
        packed[(size_t)by * N + (ibase_t + a * 256)] =
            ((ull)keyc << 32) | (ull)(unsigned)(jbase + kwin);
    }
}

// ---------------------------------------------------------------------------
// Kernel B: per-i u64-min over the 128 split slots (4 threads per point,
// 32 slots each, shuffle-min), strain quadratic form, block partials.
// Cross-tile ties (equal quantized key) resolve to smaller global j = first
// occurrence. Block covers 64 points; grid = N/64 = 192 blocks.
// ---------------------------------------------------------------------------
__global__ __launch_bounds__(256) void loss_kernel(
    const float* __restrict__ new_xyz,
    const float* __restrict__ xyz,
    const float* __restrict__ gt_sdf,
    const ull* __restrict__ packed,
    double* __restrict__ partial_sum,
    unsigned int* __restrict__ partial_cnt,
    CMat C)
{
    const int tid = threadIdx.x;
    const int il = tid >> 2;          // 0..63 : point within block
    const int chunk = tid & 3;        // 0..3  : split-chunk
    const int i = blockIdx.x * 64 + il;

    ull best = ~0ull;
    #pragma unroll 8
    for (int s = 0; s < NBY / 4; ++s) {
        const ull p = packed[(size_t)(chunk * (NBY / 4) + s) * N + i];
        best = (p < best) ? p : best;
    }
    {   // min over the 4 chunk-threads (adjacent lanes)
        ull o = __shfl_xor(best, 1, 64);
        best = (o < best) ? o : best;
        o = __shfl_xor(best, 2, 64);
        best = (o < best) ? o : best;
    }

    __shared__ ull bmin[64];
    if ((tid & 3) == 0) bmin[il] = best;
    __syncthreads();

    if (tid < 64) {
        const int ii = blockIdx.x * 64 + tid;
        const ull b = bmin[tid];
        const unsigned keyc = (unsigned)(b >> 32);
        const float d2 = __uint_as_float(keyc) - 1.0f;   // dB - 1 (quantized)
        const int nn = (int)(unsigned)(b & 0xffffffffu);

        const float nnd = sqrtf(fmaxf(d2, 0.0f));
        const bool inside = gt_sdf[ii] < 1e-8f;
        const bool valid = inside && (nnd > 1e-8f);

        float q = 0.0f;
        if (valid) {
            const float wix = new_xyz[3 * ii + 0], wiy = new_xyz[3 * ii + 1], wiz = new_xyz[3 * ii + 2];
            const float xix = xyz[3 * ii + 0], xiy = xyz[3 * ii + 1], xiz = xyz[3 * ii + 2];
            const float wnx = new_xyz[3 * nn + 0], wny = new_xyz[3 * nn + 1], wnz = new_xyz[3 * nn + 2];
            const float xnx = xyz[3 * nn + 0],     xny = xyz[3 * nn + 1],     xnz = xyz[3 * nn + 2];

            const float du = (wnx - xnx) - (wix - xix);
            const float dv = (wny - xny) - (wiy - xiy);
            const float dw = (wnz - xnz) - (wiz - xiz);
            const float dx = wnx - wix + 1e-8f;
            const float dy = wny - wiy + 1e-8f;
            const float dz = wnz - wiz + 1e-8f;

            float et[6];
            et[0] = du / dx;
            et[1] = dv / dy;
            et[2] = dw / dz;
            et[3] = (du / dy + dv / dx) * 0.5f;
            et[4] = (du / dz + dw / dx) * 0.5f;
            et[5] = (dw / dy + dv / dz) * 0.5f;

            #pragma unroll
            for (int a = 0; a < 6; ++a) {
                float s = 0.0f;
                #pragma unroll
                for (int b2 = 0; b2 < 6; ++b2) s += C.c[a][b2] * et[b2];
                q += et[a] * s;
            }
        }

        // single-wave reduction (threads 0..63 are wave 0)
        double q2 = (double)q * (double)q;
        #pragma unroll
        for (int off = 32; off > 0; off >>= 1)
            q2 += __shfl_down(q2, off, 64);
        const ull vm = __ballot(valid);
        if (tid == 0) {
            partial_sum[blockIdx.x] = q2;
            partial_cnt[blockIdx.x] = (unsigned)__popcll(vm);
        }
    }
}

// ---------------------------------------------------------------------------
// Kernel C: finalize — sum 192 partials, out = sqrt(sum q^2) / n_valid
// ---------------------------------------------------------------------------
#define NPART (N / 64)   // 192

__global__ void final_kernel(const double* __restrict__ partial_sum,
                             const unsigned int* __restrict__ partial_cnt,
                             float* __restrict__ out)
{
    const int lane = threadIdx.x;   // 64 threads
    double s = 0.0, c = 0.0;
    #pragma unroll
    for (int k = 0; k < NPART / 64; ++k) {
        s += partial_sum[lane + 64 * k];
        c += (double)partial_cnt[lane + 64 * k];
    }
    #pragma unroll
    for (int off = 32; off > 0; off >>= 1) {
        s += __shfl_down(s, off, 64);
        c += __shfl_down(c, off, 64);
    }
    if (lane == 0) out[0] = (float)(sqrt(s) / c);
}

// ---------------- Host: build C = inv(Ci) -----------------------------------
static void build_cmat(CMat* M)
{
    const double VP = 0.4, EP = 0.21;
    double A[6][12];
    memset(A, 0, sizeof(A));
    double Ci[6][6];
    memset(Ci, 0, sizeof(Ci));
    Ci[0][0] = 1.0 / EP; Ci[0][1] = -VP / EP; Ci[0][2] = -VP / EP;
    Ci[1][0] = -VP / EP; Ci[1][1] = 1.0 / EP; Ci[1][2] = -VP / EP;
    Ci[2][0] = -VP;      Ci[2][1] = -VP;      Ci[2][2] = 1.0 / EP;
    Ci[3][3] = 2.0 * (1.0 + VP) / EP;
    Ci[4][4] = Ci[3][3];
    Ci[5][5] = Ci[3][3];

    for (int i = 0; i < 6; ++i) {
        for (int j = 0; j < 6; ++j) A[i][j] = Ci[i][j];
        A[i][6 + i] = 1.0;
    }
    for (int col = 0; col < 6; ++col) {
        int piv = col;
        for (int r = col + 1; r < 6; ++r)
            if (fabs(A[r][col]) > fabs(A[piv][col])) piv = r;
        if (piv != col)
            for (int c = 0; c < 12; ++c) { double t = A[col][c]; A[col][c] = A[piv][c]; A[piv][c] = t; }
        const double d = A[col][col];
        for (int c = 0; c < 12; ++c) A[col][c] /= d;
        for (int r = 0; r < 6; ++r) {
            if (r == col) continue;
            const double f = A[r][col];
            if (f == 0.0) continue;
            for (int c = 0; c < 12; ++c) A[r][c] -= f * A[col][c];
        }
    }
    for (int i = 0; i < 6; ++i)
        for (int j = 0; j < 6; ++j)
            M->c[i][j] = (float)A[i][6 + j];
}

extern "C" void kernel_launch(void* const* d_in, const int* in_sizes, int n_in,
                              void* d_out, int out_size, void* d_ws, size_t ws_size,
                              hipStream_t stream)
{
    const float* new_xyz = (const float*)d_in[0];
    const float* xyz     = (const float*)d_in[1];
    const float* gt_sdf  = (const float*)d_in[2];
    float* out = (float*)d_out;

    // workspace layout (fully written before read — no memset needed):
    //   [0, NBY*N*8)  : packed u64 per (split, i)   (12.6 MB)
    //   then NPART doubles (partial_sum), NPART uints (partial_cnt)
    const size_t packed_bytes = (size_t)NBY * N * sizeof(ull);
    ull* packed = (ull*)d_ws;
    double* partial_sum = (double*)((char*)d_ws + packed_bytes);
    unsigned int* partial_cnt =
        (unsigned int*)((char*)partial_sum + NPART * sizeof(double));

    CMat C;
    build_cmat(&C);

    nn_kernel<<<dim3(NBX, NBY), 256, 0, stream>>>(new_xyz, gt_sdf, packed);
    loss_kernel<<<N / 64, 256, 0, stream>>>(new_xyz, xyz, gt_sdf, packed,
                                            partial_sum, partial_cnt, C);
    final_kernel<<<1, 64, 0, stream>>>(partial_sum, partial_cnt, out);
}